// Round 8
// baseline (216.307 us; speedup 1.0000x reference)
//
#include <hip/hip_runtime.h>
#include <hip/hip_bf16.h>

// Problem constants
#define BB 8
#define CIN 128
#define HH 48
#define WW 48
#define HW 2304          // 48*48
#define KK 9
#define COUT 256
#define KC 1152          // K*CIN
#define MM 18432         // B*HW
#define MT 32            // M-tile rows per block (fused kernel)
#define SFP 136          // feats LDS row stride in elements (16B-aligned)

// Barrier that waits only on LDS ops (ds_write visibility), leaving global
// loads in flight across the barrier. Correct: s_feat is double-buffered.
#define LIGHT_BARRIER() asm volatile("s_waitcnt lgkmcnt(0)\n\ts_barrier" ::: "memory")

typedef short bf16x8_t __attribute__((ext_vector_type(8)));
typedef float f32x16_t __attribute__((ext_vector_type(16)));
typedef float f32x4_t  __attribute__((ext_vector_type(4)));

static __device__ __forceinline__ float b2f(short u) {
    union { unsigned int i; float f; } c;
    c.i = ((unsigned int)(unsigned short)u) << 16;
    return c.f;
}

// ---------------------------------------------------------------------------
// PREP kernel: transpose (blocks 0..575), pack_wu (576..719),
// params MLP (720..1295; 4 positions per block, one wave each).
// ---------------------------------------------------------------------------
__global__ __launch_bounds__(256) void prep_kernel(
    const float* __restrict__ x, __hip_bfloat16* __restrict__ xT,
    const float* __restrict__ Wu, bf16x8_t* __restrict__ Bp,
    const float* __restrict__ W1, const float* __restrict__ b1,
    const float* __restrict__ W2, const float* __restrict__ b2,
    float* __restrict__ means, float* __restrict__ sigmas, int* __restrict__ fls)
{
    int bid = blockIdx.x;
    int t = threadIdx.x;

    if (bid < 576) {
        // ---- transpose x (b,c,h,w) fp32 -> xT (b,hw,c) bf16
        __shared__ float tile[64][65];
        int ij0 = (bid % 36) * 64;
        int c0  = ((bid / 36) % 2) * 64;
        int b   = bid / 72;
        int ijl = t & 63, cl = t >> 6;
        #pragma unroll
        for (int i = 0; i < 16; i++) {
            int cc = i*4 + cl;
            tile[cc][ijl] = x[(size_t)(b*CIN + c0 + cc) * HW + ij0 + ijl];
        }
        __syncthreads();
        int cl2 = t & 63, ijl2 = t >> 6;
        #pragma unroll
        for (int i = 0; i < 16; i++) {
            int ij = i*4 + ijl2;
            xT[(size_t)(b*HW + ij0 + ij) * CIN + c0 + cl2] = __float2bfloat16(tile[cl2][ij]);
        }
    } else if (bid < 720) {
        // ---- pack Wu fp32 -> bf16 fragments
        // Bp[(g*72+s)*64+lane]: Wu[g*32 + (lane&31)][s*16 + (lane>>5)*8 + j]
        int idx = (bid - 576) * 256 + t;          // 0 .. 36863
        int lane = idx & 63;
        int rest = idx >> 6;
        int s = rest % 72, g = rest / 72;
        int r = lane & 31, qq = lane >> 5;
        const float* src = Wu + (size_t)(g*32 + r) * KC + s*16 + qq*8;
        union { bf16x8_t v; __hip_bfloat16 h[8]; } o;
        #pragma unroll
        for (int j = 0; j < 8; j++) o.h[j] = __float2bfloat16(src[j]);
        Bp[idx] = o.v;
    } else {
        // ---- params MLP, wave-parallel fp64. One wave per position.
        int wave = t >> 6, lane = t & 63;
        int p = (bid - 720) * 4 + wave;           // 0..2303
        int iy = p / WW, ix = p % WW;
        float ryf = (float)iy / 47.0f;
        float rxf = (float)ix / 47.0f;
        double ry = (double)ryf, rx = (double)rxf;

        double h[8];
        #pragma unroll
        for (int jj = 0; jj < 8; jj++) {
            int j = lane*8 + jj;
            double v = ry * (double)W1[j*2+0] + rx * (double)W1[j*2+1] + (double)b1[j];
            h[jj] = v > 0.0 ? v : 0.0;
        }
        double par[27];
        #pragma unroll
        for (int o = 0; o < 27; o++) {
            const float4* w4 = (const float4*)(W2 + (size_t)o*512 + lane*8);
            float4 wa = w4[0], wb = w4[1];
            double s = (double)wa.x*h[0] + (double)wa.y*h[1]
                     + (double)wa.z*h[2] + (double)wa.w*h[3]
                     + (double)wb.x*h[4] + (double)wb.y*h[5]
                     + (double)wb.z*h[6] + (double)wb.w*h[7];
            par[o] = s;
        }
        #pragma unroll
        for (int o = 0; o < 27; o++) {
            #pragma unroll
            for (int d = 1; d < 64; d <<= 1)
                par[o] += __shfl_xor(par[o], d, 64);
            par[o] += (double)b2[o];
        }
        if (lane < KK) {
            int k = lane;
            double scy = ry * 0.9999 + 5e-05;
            double scx = rx * 0.9999 + 5e-05;
            double midy = log(scy / (1.0 - scy));
            double midx = log(scx / (1.0 - scx));
            double zy = midy + 0.1 * par[2*k+0];
            double zx = midx + 0.1 * par[2*k+1];
            double my = 47.0 / (1.0 + exp(-zy));
            double mx = 47.0 / (1.0 + exp(-zx));
            double sr = par[18 + k] + 2.0;
            double sp = (sr > 0.0 ? sr : 0.0) + log1p(exp(-fabs(sr)));
            double sg = (sp + 0.05) * 48.0 * 0.05;
            means[(p*KK + k)*2 + 0] = (float)my;
            means[(p*KK + k)*2 + 1] = (float)mx;
            sigmas[p*KK + k] = (float)sg;
            fls[(p*KK + k)*2 + 0] = (int)floor(my);
            fls[(p*KK + k)*2 + 1] = (int)floor(mx);
        }
    }
}

// ---------------------------------------------------------------------------
// FUSED gather + GEMM (R8): R4 body + light barriers + MAX OCCUPANCY.
// __launch_bounds__(512, 8): VGPR capped at 64 -> 4 blocks/CU (32 waves/CU).
// LDS 35840 B x 4 blocks = 143 KB <= 160 KB. Latency hiding via TLP (m114),
// not in-wave prefetch (R5/R7 showed ILP pipelining is compiler-defeated).
// ---------------------------------------------------------------------------
__global__ __launch_bounds__(512, 8) void fused_kernel(
    const float* __restrict__ means, const float* __restrict__ sigmas,
    const int* __restrict__ fls, const int* __restrict__ gints,
    const int* __restrict__ roff, const short* __restrict__ xT,
    const bf16x8_t* __restrict__ Bp, const float* __restrict__ bu,
    float* __restrict__ out)
{
    __shared__ int2 s_tap[KK*MT*8];                      // (lin*CIN, w bits) 18432 B
    __shared__ __align__(16) short s_feat[2][MT*SFP];    // 17408 B

    int t = threadIdx.x;
    int m0 = blockIdx.x * MT;
    int b  = m0 / HW;
    int ij0 = m0 % HW;

    // ---- setup: taps + dup-kill + normalized weights for all (row,k)
    if (t < KK*MT) {
        int p = t;
        int k = p >> 5, row = p & 31;
        int ij = ij0 + row;
        int bij = m0 + row;
        int fy = fls[(ij*KK + k)*2 + 0];
        int fx = fls[(ij*KK + k)*2 + 1];
        float my = means[(ij*KK + k)*2 + 0];
        float mx = means[(ij*KK + k)*2 + 1];
        float sg = sigmas[ij*KK + k];
        int lins[8]; float ws[8];
        #pragma unroll
        for (int v = 0; v < 8; v++) {
            int iy, ix;
            if (v < 4) {
                iy = fy + (v >> 1); ix = fx + (v & 1);
            } else if (v < 6) {
                int base = ((bij*KK + k)*2 + (v - 4)) * 2;
                iy = gints[base]; ix = gints[base + 1];
            } else {
                int base = ((bij*KK + k)*2 + (v - 6)) * 2;
                iy = fy + roff[base] - 6; ix = fx + roff[base + 1] - 6;
            }
            iy = ((iy % HH) + HH) % HH;
            ix = ((ix % WW) + WW) % WW;
            lins[v] = iy * WW + ix;
            float dy = ((float)iy - my) / sg;
            float dx = ((float)ix - mx) / sg;
            ws[v] = expf(-0.5f * (dy*dy + dx*dx));
        }
        #pragma unroll
        for (int v = 1; v < 8; v++) {
            bool dup = false;
            #pragma unroll
            for (int u = 0; u < 8; u++) if (u < v) dup = dup || (lins[u] == lins[v]);
            if (dup) ws[v] = 0.0f;
        }
        float sum = 0.0f;
        #pragma unroll
        for (int v = 0; v < 8; v++) sum += ws[v];
        float inv = 1.0f / sum;
        #pragma unroll
        for (int v = 0; v < 8; v++)
            s_tap[p*8+v] = make_int2(lins[v] * CIN, __float_as_int(ws[v] * inv));
    }
    LIGHT_BARRIER();

    const short* xb = xT + (size_t)b * (HW * CIN);
    int lane = t & 63, wave = t >> 6;
    int r = lane & 31, q = lane >> 5;
    int grow = t >> 4, gc0 = (t & 15) << 3;   // gather: row (0..31), 8-ch base

    f32x16_t acc = {};

    for (int k = 0; k < KK; k++) {
        // a) load tap data for chunk k
        bf16x8_t tap[8];
        float    wgt[8];
        {
            const int2* tp = &s_tap[(k*MT + grow)*8];
            #pragma unroll
            for (int v = 0; v < 8; v++) {
                int2 e = tp[v];
                wgt[v] = __int_as_float(e.y);
                tap[v] = *(const bf16x8_t*)(xb + e.x + gc0);
            }
        }
        // b) gather math chunk k -> LDS
        {
            float a0[8];
            #pragma unroll
            for (int j = 0; j < 8; j++) a0[j] = 0.0f;
            #pragma unroll
            for (int v = 0; v < 8; v++) {
                float w = wgt[v]; bf16x8_t d8 = tap[v];
                #pragma unroll
                for (int j = 0; j < 8; j++) a0[j] += w * b2f(d8[j]);
            }
            union { bf16x8_t v8; __hip_bfloat16 hh[8]; } o;
            #pragma unroll
            for (int j = 0; j < 8; j++) o.hh[j] = __float2bfloat16(a0[j]);
            *(bf16x8_t*)(&s_feat[k & 1][grow*SFP + gc0]) = o.v8;
        }
        // c) LDS-only barrier (any in-flight global loads stay in flight)
        LIGHT_BARRIER();
        // d) B-fragments + MFMA for chunk k
        {
            int base = (wave*72 + k*8)*64 + lane;
            const short* fb = s_feat[k & 1];
            #pragma unroll
            for (int si = 0; si < 8; si++) {
                bf16x8_t Bf = Bp[base + si*64];
                bf16x8_t a = *(const bf16x8_t*)(fb + r*SFP + si*16 + q*8);
                acc = __builtin_amdgcn_mfma_f32_32x32x16_bf16(a, Bf, acc, 0, 0, 0);
            }
        }
        // buf (k+2)&1 == k&1 is only rewritten after barrier(k+1), by which
        // time all waves' MFMA(k) ds_reads completed (lgkm waited pre-barrier)
    }

    // ---- epilogue: C col = r (n), row = (reg&3)+8*(reg>>2)+4*q
    int n = wave*32 + r;
    float bv = bu[n];
    float* oc = out + ((size_t)b * COUT + n) * HW + ij0;
    #pragma unroll
    for (int g4 = 0; g4 < 4; g4++) {
        f32x4_t vv;
        vv[0] = acc[g4*4+0] + bv;
        vv[1] = acc[g4*4+1] + bv;
        vv[2] = acc[g4*4+2] + bv;
        vv[3] = acc[g4*4+3] + bv;
        *(f32x4_t*)(oc + g4*8 + q*4) = vv;
    }
}

// ---------------------------------------------------------------------------
extern "C" void kernel_launch(void* const* d_in, const int* in_sizes, int n_in,
                              void* d_out, int out_size, void* d_ws, size_t ws_size,
                              hipStream_t stream)
{
    const float* x   = (const float*)d_in[0];
    const float* W1  = (const float*)d_in[1];
    const float* b1  = (const float*)d_in[2];
    const float* W2  = (const float*)d_in[3];
    const float* b2  = (const float*)d_in[4];
    const float* Wu  = (const float*)d_in[5];
    const float* bu  = (const float*)d_in[6];
    const int* gints = (const int*)d_in[7];
    const int* roff  = (const int*)d_in[8];
    float* out = (float*)d_out;

    char* ws = (char*)d_ws;
    float* ws_means  = (float*)(ws + 0);                    // 2304*18 fp32
    float* ws_sigma  = (float*)(ws + 165888);               // 2304*9  fp32
    int*   ws_fl     = (int*  )(ws + 248832);               // 2304*18 int
    short* ws_xT     = (short*)(ws + 414720);               // 8*2304*128 bf16
    bf16x8_t* ws_bp  = (bf16x8_t*)(ws + 5133312);           // packed Wu bf16

    prep_kernel<<<1296, 256, 0, stream>>>(x, (__hip_bfloat16*)ws_xT, Wu, ws_bp,
                                          W1, b1, W2, b2,
                                          ws_means, ws_sigma, ws_fl);
    fused_kernel<<<MM/MT, 512, 0, stream>>>(ws_means, ws_sigma, ws_fl, gints, roff,
                                            ws_xT, ws_bp, bu, out);
}

// Round 9
// 145.325 us; speedup vs baseline: 1.4884x; 1.4884x over previous
//
#include <hip/hip_runtime.h>
#include <hip/hip_bf16.h>
#include <hip/hip_fp16.h>

// Problem constants
#define BB 8
#define CIN 128
#define HH 48
#define WW 48
#define HW 2304          // 48*48
#define KK 9
#define COUT 256
#define KC 1152          // K*CIN
#define MM 18432         // B*HW
#define MT 32            // M-tile rows per block (fused kernel)
#define SFP 136          // feats LDS row stride in elements (16B-aligned)

// Barrier that waits only on LDS ops (ds_write visibility), leaving global
// loads in flight across the barrier. Correct: s_feat is double-buffered.
#define LIGHT_BARRIER() asm volatile("s_waitcnt lgkmcnt(0)\n\ts_barrier" ::: "memory")

typedef short bf16x8_t __attribute__((ext_vector_type(8)));
typedef float f32x16_t __attribute__((ext_vector_type(16)));
typedef float f32x4_t  __attribute__((ext_vector_type(4)));

static __device__ __forceinline__ float b2f(short u) {
    union { unsigned int i; float f; } c;
    c.i = ((unsigned int)(unsigned short)u) << 16;
    return c.f;
}

// ---------------------------------------------------------------------------
// PREP kernel: transpose (blocks 0..575), pack_wu (576..719),
// params MLP (720..1295; 4 positions per block, one wave each).
// ---------------------------------------------------------------------------
__global__ __launch_bounds__(256) void prep_kernel(
    const float* __restrict__ x, __hip_bfloat16* __restrict__ xT,
    const float* __restrict__ Wu, bf16x8_t* __restrict__ Bp,
    const float* __restrict__ W1, const float* __restrict__ b1,
    const float* __restrict__ W2, const float* __restrict__ b2,
    float* __restrict__ means, float* __restrict__ sigmas, int* __restrict__ fls)
{
    int bid = blockIdx.x;
    int t = threadIdx.x;

    if (bid < 576) {
        // ---- transpose x (b,c,h,w) fp32 -> xT (b,hw,c) bf16
        __shared__ float tile[64][65];
        int ij0 = (bid % 36) * 64;
        int c0  = ((bid / 36) % 2) * 64;
        int b   = bid / 72;
        int ijl = t & 63, cl = t >> 6;
        #pragma unroll
        for (int i = 0; i < 16; i++) {
            int cc = i*4 + cl;
            tile[cc][ijl] = x[(size_t)(b*CIN + c0 + cc) * HW + ij0 + ijl];
        }
        __syncthreads();
        int cl2 = t & 63, ijl2 = t >> 6;
        #pragma unroll
        for (int i = 0; i < 16; i++) {
            int ij = i*4 + ijl2;
            xT[(size_t)(b*HW + ij0 + ij) * CIN + c0 + cl2] = __float2bfloat16(tile[cl2][ij]);
        }
    } else if (bid < 720) {
        // ---- pack Wu fp32 -> bf16 fragments
        // Bp[(g*72+s)*64+lane]: Wu[g*32 + (lane&31)][s*16 + (lane>>5)*8 + j]
        int idx = (bid - 576) * 256 + t;          // 0 .. 36863
        int lane = idx & 63;
        int rest = idx >> 6;
        int s = rest % 72, g = rest / 72;
        int r = lane & 31, qq = lane >> 5;
        const float* src = Wu + (size_t)(g*32 + r) * KC + s*16 + qq*8;
        union { bf16x8_t v; __hip_bfloat16 h[8]; } o;
        #pragma unroll
        for (int j = 0; j < 8; j++) o.h[j] = __float2bfloat16(src[j]);
        Bp[idx] = o.v;
    } else {
        // ---- params MLP, wave-parallel fp64. One wave per position.
        int wave = t >> 6, lane = t & 63;
        int p = (bid - 720) * 4 + wave;           // 0..2303
        int iy = p / WW, ix = p % WW;
        float ryf = (float)iy / 47.0f;
        float rxf = (float)ix / 47.0f;
        double ry = (double)ryf, rx = (double)rxf;

        double h[8];
        #pragma unroll
        for (int jj = 0; jj < 8; jj++) {
            int j = lane*8 + jj;
            double v = ry * (double)W1[j*2+0] + rx * (double)W1[j*2+1] + (double)b1[j];
            h[jj] = v > 0.0 ? v : 0.0;
        }
        double par[27];
        #pragma unroll
        for (int o = 0; o < 27; o++) {
            const float4* w4 = (const float4*)(W2 + (size_t)o*512 + lane*8);
            float4 wa = w4[0], wb = w4[1];
            double s = (double)wa.x*h[0] + (double)wa.y*h[1]
                     + (double)wa.z*h[2] + (double)wa.w*h[3]
                     + (double)wb.x*h[4] + (double)wb.y*h[5]
                     + (double)wb.z*h[6] + (double)wb.w*h[7];
            par[o] = s;
        }
        #pragma unroll
        for (int o = 0; o < 27; o++) {
            #pragma unroll
            for (int d = 1; d < 64; d <<= 1)
                par[o] += __shfl_xor(par[o], d, 64);
            par[o] += (double)b2[o];
        }
        if (lane < KK) {
            int k = lane;
            double scy = ry * 0.9999 + 5e-05;
            double scx = rx * 0.9999 + 5e-05;
            double midy = log(scy / (1.0 - scy));
            double midx = log(scx / (1.0 - scx));
            double zy = midy + 0.1 * par[2*k+0];
            double zx = midx + 0.1 * par[2*k+1];
            double my = 47.0 / (1.0 + exp(-zy));
            double mx = 47.0 / (1.0 + exp(-zx));
            double sr = par[18 + k] + 2.0;
            double sp = (sr > 0.0 ? sr : 0.0) + log1p(exp(-fabs(sr)));
            double sg = (sp + 0.05) * 48.0 * 0.05;
            means[(p*KK + k)*2 + 0] = (float)my;
            means[(p*KK + k)*2 + 1] = (float)mx;
            sigmas[p*KK + k] = (float)sg;
            fls[(p*KK + k)*2 + 0] = (int)floor(my);
            fls[(p*KK + k)*2 + 1] = (int)floor(mx);
        }
    }
}

// ---------------------------------------------------------------------------
// FUSED gather + GEMM (R9): R4 body at (512,4) — the known no-spill config —
// + XCD swizzle (b = bid & 7: each XCD works ONE 4.7MB batch image, ~L2-
// resident vs 37.7MB working set without swizzle) + light barriers +
// s_tap packed to 4 B (lin<<16 | fp16 weight; validated R6).
// ---------------------------------------------------------------------------
__global__ __launch_bounds__(512, 4) void fused_kernel(
    const float* __restrict__ means, const float* __restrict__ sigmas,
    const int* __restrict__ fls, const int* __restrict__ gints,
    const int* __restrict__ roff, const short* __restrict__ xT,
    const bf16x8_t* __restrict__ Bp, const float* __restrict__ bu,
    float* __restrict__ out)
{
    __shared__ unsigned int s_tap[KK*MT*8];              // 9216 B
    __shared__ __align__(16) short s_feat[2][MT*SFP];    // 17408 B

    int t = threadIdx.x;
    // XCD swizzle: blocks with bid&7 == b land on XCD b (round-robin
    // dispatch), so each XCD streams one batch image (4.7 MB ~ 4 MiB L2).
    int b   = blockIdx.x & 7;
    int grp = blockIdx.x >> 3;          // 0..71 within batch
    int ij0 = grp * MT;
    int m0  = b * HW + ij0;

    // ---- setup: taps + dup-kill + normalized weights for all (row,k)
    if (t < KK*MT) {
        int p = t;
        int k = p >> 5, row = p & 31;
        int ij = ij0 + row;
        int bij = m0 + row;
        int fy = fls[(ij*KK + k)*2 + 0];
        int fx = fls[(ij*KK + k)*2 + 1];
        float my = means[(ij*KK + k)*2 + 0];
        float mx = means[(ij*KK + k)*2 + 1];
        float sg = sigmas[ij*KK + k];
        int lins[8]; float ws[8];
        #pragma unroll
        for (int v = 0; v < 8; v++) {
            int iy, ix;
            if (v < 4) {
                iy = fy + (v >> 1); ix = fx + (v & 1);
            } else if (v < 6) {
                int base = ((bij*KK + k)*2 + (v - 4)) * 2;
                iy = gints[base]; ix = gints[base + 1];
            } else {
                int base = ((bij*KK + k)*2 + (v - 6)) * 2;
                iy = fy + roff[base] - 6; ix = fx + roff[base + 1] - 6;
            }
            iy = ((iy % HH) + HH) % HH;
            ix = ((ix % WW) + WW) % WW;
            lins[v] = iy * WW + ix;
            float dy = ((float)iy - my) / sg;
            float dx = ((float)ix - mx) / sg;
            ws[v] = expf(-0.5f * (dy*dy + dx*dx));
        }
        #pragma unroll
        for (int v = 1; v < 8; v++) {
            bool dup = false;
            #pragma unroll
            for (int u = 0; u < 8; u++) if (u < v) dup = dup || (lins[u] == lins[v]);
            if (dup) ws[v] = 0.0f;
        }
        float sum = 0.0f;
        #pragma unroll
        for (int v = 0; v < 8; v++) sum += ws[v];
        float inv = 1.0f / sum;
        #pragma unroll
        for (int v = 0; v < 8; v++) {
            unsigned short hb = __half_as_ushort(__float2half(ws[v] * inv));
            s_tap[p*8+v] = ((unsigned int)lins[v] << 16) | (unsigned int)hb;
        }
    }
    LIGHT_BARRIER();

    const short* xb = xT + (size_t)b * (HW * CIN);
    int lane = t & 63, wave = t >> 6;
    int r = lane & 31, q = lane >> 5;
    int grow = t >> 4, gc0 = (t & 15) << 3;   // gather: row (0..31), 8-ch base

    f32x16_t acc = {};

    for (int k = 0; k < KK; k++) {
        // a) load tap data for chunk k
        bf16x8_t tap[8];
        float    wgt[8];
        {
            const unsigned int* tp = &s_tap[(k*MT + grow)*8];
            #pragma unroll
            for (int v = 0; v < 8; v++) {
                unsigned int e = tp[v];
                wgt[v] = __half2float(__ushort_as_half((unsigned short)(e & 0xffffu)));
                tap[v] = *(const bf16x8_t*)(xb + (size_t)(e >> 16) * CIN + gc0);
            }
        }
        // b) gather math chunk k -> LDS
        {
            float a0[8];
            #pragma unroll
            for (int j = 0; j < 8; j++) a0[j] = 0.0f;
            #pragma unroll
            for (int v = 0; v < 8; v++) {
                float w = wgt[v]; bf16x8_t d8 = tap[v];
                #pragma unroll
                for (int j = 0; j < 8; j++) a0[j] += w * b2f(d8[j]);
            }
            union { bf16x8_t v8; __hip_bfloat16 hh[8]; } o;
            #pragma unroll
            for (int j = 0; j < 8; j++) o.hh[j] = __float2bfloat16(a0[j]);
            *(bf16x8_t*)(&s_feat[k & 1][grow*SFP + gc0]) = o.v8;
        }
        // c) LDS-only barrier (in-flight global loads stay in flight)
        LIGHT_BARRIER();
        // d) B-fragments + MFMA for chunk k
        {
            int base = (wave*72 + k*8)*64 + lane;
            const short* fb = s_feat[k & 1];
            #pragma unroll
            for (int si = 0; si < 8; si++) {
                bf16x8_t Bf = Bp[base + si*64];
                bf16x8_t a = *(const bf16x8_t*)(fb + r*SFP + si*16 + q*8);
                acc = __builtin_amdgcn_mfma_f32_32x32x16_bf16(a, Bf, acc, 0, 0, 0);
            }
        }
        // buf (k+2)&1 == k&1 only rewritten after barrier(k+1): safe.
    }

    // ---- epilogue: C col = r (n), row = (reg&3)+8*(reg>>2)+4*q
    int n = wave*32 + r;
    float bv = bu[n];
    float* oc = out + ((size_t)b * COUT + n) * HW + ij0;
    #pragma unroll
    for (int g4 = 0; g4 < 4; g4++) {
        f32x4_t vv;
        vv[0] = acc[g4*4+0] + bv;
        vv[1] = acc[g4*4+1] + bv;
        vv[2] = acc[g4*4+2] + bv;
        vv[3] = acc[g4*4+3] + bv;
        *(f32x4_t*)(oc + g4*8 + q*4) = vv;
    }
}

// ---------------------------------------------------------------------------
extern "C" void kernel_launch(void* const* d_in, const int* in_sizes, int n_in,
                              void* d_out, int out_size, void* d_ws, size_t ws_size,
                              hipStream_t stream)
{
    const float* x   = (const float*)d_in[0];
    const float* W1  = (const float*)d_in[1];
    const float* b1  = (const float*)d_in[2];
    const float* W2  = (const float*)d_in[3];
    const float* b2  = (const float*)d_in[4];
    const float* Wu  = (const float*)d_in[5];
    const float* bu  = (const float*)d_in[6];
    const int* gints = (const int*)d_in[7];
    const int* roff  = (const int*)d_in[8];
    float* out = (float*)d_out;

    char* ws = (char*)d_ws;
    float* ws_means  = (float*)(ws + 0);                    // 2304*18 fp32
    float* ws_sigma  = (float*)(ws + 165888);               // 2304*9  fp32
    int*   ws_fl     = (int*  )(ws + 248832);               // 2304*18 int
    short* ws_xT     = (short*)(ws + 414720);               // 8*2304*128 bf16
    bf16x8_t* ws_bp  = (bf16x8_t*)(ws + 5133312);           // packed Wu bf16

    prep_kernel<<<1296, 256, 0, stream>>>(x, (__hip_bfloat16*)ws_xT, Wu, ws_bp,
                                          W1, b1, W2, b2,
                                          ws_means, ws_sigma, ws_fl);
    fused_kernel<<<MM/MT, 512, 0, stream>>>(ws_means, ws_sigma, ws_fl, gints, roff,
                                            ws_xT, ws_bp, bu, out);
}